// Round 7
// baseline (37.116 us; speedup 1.0000x reference)
//
#include <hip/hip_runtime.h>

// YOLOv1 loss, forward only. preds/targets: (16384,7,7,30) f32 -> scalar f32.
//   coo=(T4>0), noo=(T4==0)
//   noobj   = noo * ((P4-T4)^2 + (P9-T9)^2)
//   iou_b   = IoU(pred box b, pred box 0)   (reference quirk: tbox = pred box 0)
//   idx     = argmax(iou)  [np: first max; NaN acts as max]
//   loss += coo*((P[5i+4]-max_iou)^2 + 0.5*P[5(1-i)+4]^2) + 0.5*noobj
// total = sum / 16384.  (loc_loss and class_loss are exactly 0.)
//
// R6: async DMA staging via __builtin_amdgcn_global_load_lds (width 16).
// R5 failed because the compiler sank register-prefetch (VGPR=32) -- at HIP
// level only the DMA path guarantees issue order. Global source is PER-LANE
// (gather the needed columns), LDS dest is linear base+lane*16 -> compact
// layout lands for free. 2 tiles/block, all 10 DMAs issued back-to-back,
// ONE barrier (its vmcnt(0) drain waits on fully-parallel flight), then
// compute both tiles. 40KB LDS -> 4 blocks/CU.
//
// Column map per pair (2 cells = 15 float4 per array):
//   preds r in {0,1,2,7,8,9} -> LDS slot 6p+rr:
//     even cell: ch0-3 = P[6p], ch4-7 = P[6p+1], ch8,9 = P[6p+2].xy
//     odd  cell: ch0,1 = P[6p+3].zw, ch2-5 = P[6p+4], ch6-9 = P[6p+5]
//   targets r in {1,2,8,9} -> LDS slot 4p+rr:
//     even: t4 = T[4p].x,   t9 = T[4p+1].y
//     odd:  t4 = T[4p+2].z, t9 = T[4p+3].w

#define TILE 256   // cells per tile; 128 pairs
#define NT   2     // tiles per block -> grid 1568

__device__ __forceinline__ void gld16(const void* g, void* lds) {
    __builtin_amdgcn_global_load_lds(
        (const __attribute__((address_space(1))) void*)g,
        (__attribute__((address_space(3))) void*)lds,
        16, 0, 0);
}

__device__ __forceinline__ float cell_loss(const float p[10], float t4, float t9) {
    float coo = (t4 > 0.0f) ? 1.0f : 0.0f;
    float noo = (t4 == 0.0f) ? 1.0f : 0.0f;

    float d4 = p[4] - t4;
    float d9 = p[9] - t9;
    float noo_term = noo * (d4 * d4 + d9 * d9);

    // "target" box for IoU = pred box 0 (reference quirk)
    float lt2x = p[0] / 14.0f - 0.5f * p[2];
    float lt2y = p[1] / 14.0f - 0.5f * p[3];
    float rb2x = p[0] / 14.0f + 0.5f * p[2];
    float rb2y = p[1] / 14.0f + 0.5f * p[3];
    float area2 = (rb2x - lt2x) * (rb2y - lt2y);

    float iou[2];
    #pragma unroll
    for (int b = 0; b < 2; ++b) {
        float x = p[5 * b] / 14.0f;
        float y = p[5 * b + 1] / 14.0f;
        float w = p[5 * b + 2];
        float h = p[5 * b + 3];
        float lt1x = x - 0.5f * w, lt1y = y - 0.5f * h;
        float rb1x = x + 0.5f * w, rb1y = y + 0.5f * h;
        float iltx = fmaxf(lt1x, lt2x), ilty = fmaxf(lt1y, lt2y);
        float irbx = fminf(rb1x, rb2x), irby = fminf(rb1y, rb2y);
        float iwx = fmaxf(irbx - iltx, 0.0f);
        float iwy = fmaxf(irby - ilty, 0.0f);
        float inter = iwx * iwy;
        float area1 = (rb1x - lt1x) * (rb1y - lt1y);
        iou[b] = inter / (area1 + area2 - inter);
    }

    // np.argmax: first occurrence of max; NaN compares as maximum.
    int idx;
    float max_iou;
    if (isnan(iou[0]))      { idx = 0; max_iou = iou[0]; }
    else if (isnan(iou[1])) { idx = 1; max_iou = iou[1]; }
    else                    { idx = (iou[1] > iou[0]) ? 1 : 0;
                              max_iou = fmaxf(iou[0], iou[1]); }

    float resp4  = p[5 * idx + 4];
    float nresp4 = p[5 * (1 - idx) + 4];
    float cdiff  = resp4 - max_iou;
    return coo * (cdiff * cdiff + 0.5f * nresp4 * nresp4) + 0.5f * noo_term;
}

// issue 5 DMA gathers for one tile: preds -> ldsP[768 float4], targets -> ldsT[512]
__device__ __forceinline__ void stage_tile(const float4* __restrict__ gp,
                                           const float4* __restrict__ gt,
                                           float4* ldsP, float4* ldsT, int tid) {
    const int wid = tid >> 6;
    #pragma unroll
    for (int k = 0; k < 3; ++k) {              // 768 = 128 pairs * 6 pred cols
        int L = k * 256 + tid;
        int pair = L / 6, rr = L - pair * 6;
        int r = (rr < 3) ? rr : rr + 4;        // {0,1,2,7,8,9}
        gld16(gp + pair * 15 + r, ldsP + k * 256 + wid * 64);
    }
    #pragma unroll
    for (int k = 0; k < 2; ++k) {              // 512 = 128 pairs * 4 target cols
        int L = k * 256 + tid;
        int pair = L >> 2, rr = L & 3;
        int r = (rr < 2) ? rr + 1 : rr + 6;    // {1,2,8,9}
        gld16(gt + pair * 15 + r, ldsT + k * 256 + wid * 64);
    }
}

__device__ __forceinline__ float compute_tile(const float4* P, const float4* T, int tid) {
    const int pr = tid >> 1;
    float p[10];
    if ((tid & 1) == 0) {
        float4 a = P[6 * pr], b = P[6 * pr + 1], c = P[6 * pr + 2];
        p[0]=a.x; p[1]=a.y; p[2]=a.z; p[3]=a.w;
        p[4]=b.x; p[5]=b.y; p[6]=b.z; p[7]=b.w;
        p[8]=c.x; p[9]=c.y;
        float t4 = reinterpret_cast<const float*>(T + 4 * pr)[0];      // slot.x
        float t9 = reinterpret_cast<const float*>(T + 4 * pr + 1)[1];  // slot.y
        return cell_loss(p, t4, t9);
    } else {
        float4 a = P[6 * pr + 3], b = P[6 * pr + 4], c = P[6 * pr + 5];
        p[0]=a.z; p[1]=a.w;
        p[2]=b.x; p[3]=b.y; p[4]=b.z; p[5]=b.w;
        p[6]=c.x; p[7]=c.y; p[8]=c.z; p[9]=c.w;
        float t4 = reinterpret_cast<const float*>(T + 4 * pr + 2)[2];  // slot.z
        float t9 = reinterpret_cast<const float*>(T + 4 * pr + 3)[3];  // slot.w
        return cell_loss(p, t4, t9);
    }
}

__global__ __launch_bounds__(256) void yolo_loss_kernel(
    const float* __restrict__ preds,
    const float* __restrict__ targets,
    float* __restrict__ partials,
    int ncells)
{
    // tile0: P [0,768) T [768,1280) | tile1: P [1280,2048) T [2048,2560)
    __shared__ float4 smem[2560];                     // 40 KB
    float* warp_sums = reinterpret_cast<float*>(smem);  // aliased; see safety note

    const int tid = threadIdx.x;
    const long tA = (long)blockIdx.x * (NT * TILE);
    const long tB = tA + TILE;
    float contrib = 0.0f;

    if (tB + TILE <= ncells) {
        // issue ALL 10 DMAs back-to-back, then one drain
        stage_tile(reinterpret_cast<const float4*>(preds + tA * 30),
                   reinterpret_cast<const float4*>(targets + tA * 30),
                   smem, smem + 768, tid);
        stage_tile(reinterpret_cast<const float4*>(preds + tB * 30),
                   reinterpret_cast<const float4*>(targets + tB * 30),
                   smem + 1280, smem + 2048, tid);
        __syncthreads();   // vmcnt(0) drain: all 10 in-flight DMAs complete here

        contrib  = compute_tile(smem, smem + 768, tid);
        contrib += compute_tile(smem + 1280, smem + 2048, tid);
    } else {
        // generic tail fallback (unused: 802816 = 1568 * 512): direct loads
        #pragma unroll
        for (int t = 0; t < NT; ++t) {
            long cell = tA + (long)t * TILE + tid;
            if (cell < ncells) {
                long base = cell * 30;
                float p[10];
                #pragma unroll
                for (int k = 0; k < 5; ++k) {
                    float2 v = *reinterpret_cast<const float2*>(preds + base + 2 * k);
                    p[2 * k] = v.x;
                    p[2 * k + 1] = v.y;
                }
                contrib += cell_loss(p, targets[base + 4], targets[base + 9]);
            }
        }
    }

    // wave (64-lane) shuffle reduce
    #pragma unroll
    for (int off = 32; off > 0; off >>= 1)
        contrib += __shfl_down(contrib, off, 64);

    // warp_sums aliases smem[0] (16B). Safe: only lane0 of each wave writes,
    // after that wave finished all its LDS reads (same-wave program order);
    // smem[0..3] floats are only ever read by tids 0,1 (wave 0) in compute.
    int lane = tid & 63;
    int wid  = tid >> 6;
    __syncthreads();                 // all compute reads done before aliasing write
    if (lane == 0) warp_sums[wid] = contrib;
    __syncthreads();

    if (tid == 0) {
        partials[blockIdx.x] = warp_sums[0] + warp_sums[1] + warp_sums[2] + warp_sums[3];
    }
}

__global__ __launch_bounds__(256) void yolo_reduce_kernel(
    const float* __restrict__ partials,
    float* __restrict__ out,
    int nparts)
{
    __shared__ float warp_sums[4];
    const int tid = threadIdx.x;

    float s = 0.0f;
    for (int i = tid; i < nparts; i += 256)
        s += partials[i];

    #pragma unroll
    for (int off = 32; off > 0; off >>= 1)
        s += __shfl_down(s, off, 64);

    int lane = tid & 63;
    int wid  = tid >> 6;
    if (lane == 0) warp_sums[wid] = s;
    __syncthreads();

    if (tid == 0) {
        out[0] = (warp_sums[0] + warp_sums[1] + warp_sums[2] + warp_sums[3])
                 * (1.0f / 16384.0f);
    }
}

extern "C" void kernel_launch(void* const* d_in, const int* in_sizes, int n_in,
                              void* d_out, int out_size, void* d_ws, size_t ws_size,
                              hipStream_t stream) {
    const float* preds   = (const float*)d_in[0];
    const float* targets = (const float*)d_in[1];
    float* out = (float*)d_out;
    float* partials = (float*)d_ws;

    int ncells = in_sizes[0] / 30;                       // 802816
    int grid = (ncells + NT * TILE - 1) / (NT * TILE);   // 1568

    yolo_loss_kernel<<<grid, 256, 0, stream>>>(preds, targets, partials, ncells);
    yolo_reduce_kernel<<<1, 256, 0, stream>>>(partials, out, grid);
}